// Round 4
// baseline (122.559 us; speedup 1.0000x reference)
//
#include <hip/hip_runtime.h>

// IndexedLinear: out[z, s*V:(s+1)*V] = coeff[s] * x[z, s*U:(s+1)*U] @ W[seg(z), s]
// S=8, U=V=32, C=32 segments, Z=65536. HBM-bound: ~128 MiB -> ~20.5us @ 6.3TB/s.
//
// R9 == R8 with ONE change: regular stores instead of __builtin_nontemporal_store.
// Evidence trail: R5 (sync-drain LDS) 117.9, R6 (counted-vmcnt dbuf) 118.2,
// R8 (zero-LDS direct) 120.7 -- three disjoint structures, same time. Kernel
// itself ~33-36us (absent from top-5; bench includes ~85us of 256MiB harness
// fills @42us). The only memory-path invariant across ALL rounds is the `nt`
// store flag. nt = no-allocate, bypasses L2 write-combining; the harness fill
// (normal stores) sustains 6.3 TB/s, our nt-writing kernels all sit at ~3.9.
// Single-variable test: drop nt. Stores are full-line (32 lanes x 4B
// contiguous per half-wave), so allocating stores incur no RFO traffic.
//
// Everything else identical to R8:
//  - zero LDS, no barriers; 4 independent waves/block; grid 2048.
//  - A: lane (m,h) loads its contiguous 32B row slices (8x dwordx4).
//  - B: W slice L2-hot, coeff folded, packed v_cvt_pk_bf16_f32 (RNE,
//    bit-identical to verified f2bf).
//  - verified C/D map: reg r -> row (r&3)+8*(r>>2)+4h, col m.
//  - fp32-exact fallback for segment-boundary blocks (never taken for the
//    uniform counts=2048 input, but required for correctness in general).

constexpr int S = 8, U = 32, V = 32, C = 32, Z = 65536;
constexpr int SU = S * U;   // 256 floats per X row
constexpr int SV = S * V;   // 256 floats per out row
constexpr int NT = 256;     // 4 waves
constexpr int BZ = 32;      // z rows per block; wave w handles s in {2w, 2w+1}

typedef float    f4     __attribute__((ext_vector_type(4)));
typedef float    f32x16 __attribute__((ext_vector_type(16)));
typedef short    bf16x8 __attribute__((ext_vector_type(8)));
typedef unsigned u32x4  __attribute__((ext_vector_type(4)));

// packed RNE f32x2 -> bf16x2 (low = lo, high = hi)
__device__ __forceinline__ unsigned cvtpk(float lo, float hi) {
  unsigned r;
  asm("v_cvt_pk_bf16_f32 %0, %1, %2" : "=v"(r) : "v"(lo), "v"(hi));
  return r;
}

__global__ __launch_bounds__(NT) void IndexedLinear_kernel(
    const float* __restrict__ W_all,   // (C, S*U*V)
    const float* __restrict__ X,       // (Z, S*U)
    const int*   __restrict__ counts,  // (C,)
    const float* __restrict__ coeff,   // (S,)
    float*       __restrict__ out)     // (Z, S*V)
{
  const int tid  = threadIdx.x;
  const int lane = tid & 63;
  const int w    = tid >> 6;
  const int z0   = blockIdx.x * BZ;

  const int m  = lane & 31;   // A row / B col / C col
  const int h  = lane >> 5;   // k-half
  const int s0 = 2 * w;

  // ---- segment exclusive-prefix scan (per wave, no cross-wave dependency) --
  int cnt = (lane < C) ? counts[lane] : 0;
  int inc = cnt;
  #pragma unroll
  for (int d = 1; d < 32; d <<= 1) {
    int o = __shfl_up(inc, d, 64);
    if (lane >= d) inc += o;
  }
  const int exc = inc - cnt;
  const unsigned long long ma = __ballot(lane < C && exc <= z0);
  const unsigned long long mb = __ballot(lane < C && exc <= z0 + BZ - 1);
  const int segA = __popcll(ma) - 1;
  const int segB = __popcll(mb) - 1;
  const bool uni = (segA == segB);

  if (uni) {
    // ---- A: direct global loads, lane (m,h) reads its contiguous 32B row
    //      slices for both s-tiles (8x global_load_dwordx4, max MLP) ----
    const f4* Xr = (const f4*)X + (size_t)(z0 + m) * (SU / 4) + 2 * h;
    f4 xs[8];
    #pragma unroll
    for (int tt = 0; tt < 2; ++tt) {
      const int c0 = (s0 + tt) * 8;
      xs[4 * tt + 0] = Xr[c0 + 0];   // a1 lo:  k = 8h   .. 8h+4
      xs[4 * tt + 1] = Xr[c0 + 1];   // a1 hi:  k = 8h+4 .. 8h+8
      xs[4 * tt + 2] = Xr[c0 + 4];   // a2 lo:  k = 16+8h ..
      xs[4 * tt + 3] = Xr[c0 + 5];   // a2 hi
    }

    // ---- B fragments (L2-hot W, coeff folded), packed converts ----
    const float* wseg = W_all + (size_t)segA * (S * U * V);
    u32x4 b1[2], b2[2];
    #pragma unroll
    for (int tt = 0; tt < 2; ++tt) {
      const int s = s0 + tt;
      const float cs = coeff[s];
      const float* wb = wseg + s * (U * V) + m;
      #pragma unroll
      for (int j = 0; j < 4; ++j) {
        b1[tt][j] = cvtpk(wb[(8 * h + 2 * j) * V] * cs,
                          wb[(8 * h + 2 * j + 1) * V] * cs);
        b2[tt][j] = cvtpk(wb[(16 + 8 * h + 2 * j) * V] * cs,
                          wb[(16 + 8 * h + 2 * j + 1) * V] * cs);
      }
    }

    #pragma unroll
    for (int tt = 0; tt < 2; ++tt) {
      const int s = s0 + tt;
      const f4 xa = xs[4 * tt + 0], xb = xs[4 * tt + 1];
      const f4 xc = xs[4 * tt + 2], xd = xs[4 * tt + 3];
      u32x4 pa, pb;
      pa[0] = cvtpk(xa[0], xa[1]); pa[1] = cvtpk(xa[2], xa[3]);
      pa[2] = cvtpk(xb[0], xb[1]); pa[3] = cvtpk(xb[2], xb[3]);
      pb[0] = cvtpk(xc[0], xc[1]); pb[1] = cvtpk(xc[2], xc[3]);
      pb[2] = cvtpk(xd[0], xd[1]); pb[3] = cvtpk(xd[2], xd[3]);
      const bf16x8 a1 = __builtin_bit_cast(bf16x8, pa);
      const bf16x8 a2 = __builtin_bit_cast(bf16x8, pb);
      f32x16 acc = {};
      acc = __builtin_amdgcn_mfma_f32_32x32x16_bf16(
          a1, __builtin_bit_cast(bf16x8, b1[tt]), acc, 0, 0, 0);
      acc = __builtin_amdgcn_mfma_f32_32x32x16_bf16(
          a2, __builtin_bit_cast(bf16x8, b2[tt]), acc, 0, 0, 0);

      // verified C/D map: reg r -> row (r&3)+8*(r>>2)+4h, col m.
      // each store instr covers 2 full 128B lines (h=0: row R; h=1: row R+4).
      // R9: plain allocating stores (was nontemporal) -- L2 write-combining.
      float* ob = out + (size_t)z0 * SV + s * V + m;
      #pragma unroll
      for (int r = 0; r < 16; ++r) {
        const int row = (r & 3) + 8 * (r >> 2) + 4 * h;
        ob[(size_t)row * SV] = acc[r];
      }
    }
  } else {
    // ---- fallback: block crosses a segment boundary (fp32 exact) ----
    const int zz = z0 + m;
    int sg = 0;
    #pragma unroll 1
    for (int i = 1; i < C; ++i) {
      const int pi = __shfl(exc, i, 64);
      if (pi <= zz) sg = i;
    }
    #pragma unroll 1
    for (int tt = 0; tt < 2; ++tt) {
      const int s = s0 + tt;
      const float cs = coeff[s];
      const float* wr = W_all + (size_t)sg * (S * U * V) + s * (U * V) + 16 * h;
      float accv[16] = {};
      #pragma unroll 1
      for (int cq = 0; cq < 8; ++cq) {
        const f4 xv = ((const f4*)X)[(size_t)zz * (SU / 4) + s * 8 + cq];
        #pragma unroll
        for (int ii = 0; ii < 4; ++ii) {
          const int u = cq * 4 + ii;
          const float xu = xv[ii];
          #pragma unroll
          for (int j = 0; j < 16; ++j) accv[j] += xu * wr[u * V + j];
        }
      }
      float* ob = out + (size_t)zz * SV + s * V + 16 * h;
      #pragma unroll
      for (int j = 0; j < 16; ++j) ob[j] = accv[j] * cs;
    }
  }
}

extern "C" void kernel_launch(void* const* d_in, const int* in_sizes, int n_in,
                              void* d_out, int out_size, void* d_ws, size_t ws_size,
                              hipStream_t stream) {
  const float* input1       = (const float*)d_in[0];  // (C, S*U*V)
  const float* input2       = (const float*)d_in[1];  // (Z, S*U)
  const int*   counts       = (const int*)d_in[2];    // (C,)
  const float* coefficients = (const float*)d_in[3];  // (S,)
  float*       out          = (float*)d_out;          // (Z, S*V)

  const int grid = Z / BZ;  // 2048 blocks, 4 independent waves each, no LDS
  IndexedLinear_kernel<<<grid, NT, 0, stream>>>(input1, input2, counts,
                                                coefficients, out);
}